// Round 19
// baseline (103.896 us; speedup 1.0000x reference)
//
#include <hip/hip_runtime.h>
#include <hip/hip_bf16.h>

// Problem constants (from reference)
#define B_    8
#define C_    128
#define H_    64
#define W_    64
#define COUT_ 128
#define K2_   9
#define JOFF_ 18            // 2*K*K offset channels
#define HW_   (H_*W_)       // 4096
#define CK_   (C_*K2_)      // 1152

typedef short  short8 __attribute__((ext_vector_type(8)));   // 8 bf16 in 4 VGPR
typedef float  f32x4  __attribute__((ext_vector_type(4)));

__device__ __forceinline__ ushort f2bf(float f) {
    __hip_bfloat16 h = __float2bfloat16(f);
    return *reinterpret_cast<ushort*>(&h);
}
__device__ __forceinline__ float bf2f(ushort u) {
    return __uint_as_float(((uint)u) << 16);
}
// RNE-to-bf16 rounding kept in the HIGH 16 bits (bit-identical to
// __float2bfloat16 for non-NaN inputs): u + 0x7FFF + lsb(u>>16).
__device__ __forceinline__ uint bfround(float f) {
    uint u = __float_as_uint(f);
    return u + 0x7FFFu + ((u >> 16) & 1u);
}
// pack two rounded values: low16 = hi16(r0), high16 = hi16(r1) — one v_perm
__device__ __forceinline__ uint bfpack(float v0, float v1) {
    return __builtin_amdgcn_perm(bfround(v1), bfround(v0), 0x07060302u);
}

// ---------------------------------------------------------------------------
// Kernel X: x NCHW f32 -> xt NHWC bf16 ([b][hw][c], c fastest).
// ---------------------------------------------------------------------------
__global__ __launch_bounds__(512) void nhwc_kernel(
    const float* __restrict__ x, ushort* __restrict__ xt)
{
    __shared__ float tile[64][65];
    const int blk = blockIdx.x;            // 8 b * 2 ct * 64 ht = 1024
    const int ht = blk & 63;
    const int ct = (blk >> 6) & 1;
    const int b  = blk >> 7;
    const int t  = threadIdx.x;
    const int tx = t & 63, ty = t >> 6;    // ty 0..7

    const float* xs = x + ((size_t)(b * C_ + ct * 64) << 12) + (ht << 6);
#pragma unroll
    for (int i = 0; i < 8; ++i) {
        int c = i * 8 + ty;
        tile[c][tx] = xs[((size_t)c << 12) + tx];
    }
    __syncthreads();

    const int r  = t >> 3;                 // position 0..63
    const int co = (t & 7) * 8;            // channel octet
    short8 pack;
#pragma unroll
    for (int j = 0; j < 8; ++j) pack[j] = (short)f2bf(tile[co + j][r]);
    *reinterpret_cast<short8*>(
        xt + ((((size_t)b << 12) + (ht << 6) + r) << 7) + ct * 64 + co) = pack;
}

// ---------------------------------------------------------------------------
// Kernel T: both weight transposes.
//   wt     [k][o][c]  bf16 (tap-major)             deform GEMM A
//   wt_off [k][j32][c] bf16 (tap-major, rows 18..31 zero)  offset GEMM A
// ---------------------------------------------------------------------------
__global__ __launch_bounds__(256) void transpose_w_kernel(
    const float* __restrict__ w_def, const float* __restrict__ w_off,
    ushort* __restrict__ wt, ushort* __restrict__ wt_off)
{
    int t = blockIdx.x * 256 + threadIdx.x;
    if (t < K2_ * COUT_ * C_) {
        int c = t & 127;
        int o = (t >> 7) & 127;
        int k = t >> 14;
        float v = w_def[((size_t)o * C_ + c) * K2_ + k];
        wt[((size_t)k * COUT_ + o) * C_ + c] = f2bf(v);
    } else {
        int i = t - K2_ * COUT_ * C_;
        if (i < K2_ * 32 * C_) {
            int c = i & 127;
            int j = (i >> 7) & 31;
            int k = i >> 12;
            float v = (j < JOFF_) ? w_off[((size_t)j * C_ + c) * K2_ + k] : 0.f;
            wt_off[(((size_t)k * 32) + j) * C_ + c] = f2bf(v);
        }
    }
}

// ---------------------------------------------------------------------------
// Kernel B: offset conv (LDS-staged MFMA prologue) + fused deformable
// gather + MFMA GEMM. NEW GEOMETRY: tile = 128 out-ch x 32 positions ->
// 1024 blocks; launch_bounds(512,6) (85 VGPR cap -> 6 waves/SIMD = 24
// waves/CU = 3 independent barrier groups, vs r18's 2). Per-thread state
// shrunk to fit: acc[2], single aC (post-MFMA reload + sched_barrier —
// r12 trick), gather = 4x16B corner loads (gp=t>>4, gq=t&15: instruction
// = 8 positions x 2 chunks -> ~8 cachelines, r13 TA mapping preserved).
// Static depth-2 gather pipeline (gA/gB, compile-time parity — r16).
// ---------------------------------------------------------------------------
__global__ __launch_bounds__(512, 6) void deform_mfma_kernel(
    const ushort* __restrict__ xt, const ushort* __restrict__ wt,
    const ushort* __restrict__ wt_off, const float* __restrict__ b_off,
    float* __restrict__ out)
{
    __shared__ __align__(16) ushort smem[3 * 34 * C_];   // 26112 B union
    __shared__ float s_off[JOFF_][32];                   // 2304 B

    typedef ushort sB_t[2][32][C_];                      // 16384 B view
    typedef ushort pro_t[3][34][C_];                     // 26112 B view
    sB_t&  sB  = *reinterpret_cast<sB_t*>(smem);
    pro_t& pro = *reinterpret_cast<pro_t*>(smem);

    const int bid  = blockIdx.x;             // 1024 blocks
    const int nbid = ((bid & 7) << 7) + (bid >> 3);   // XCD chunk: 1 image/XCD
    const int s0   = nbid << 5;
    const int b    = s0 >> 12;
    const int hw0  = s0 & (HW_ - 1);
    const int ho   = hw0 >> 6;
    const int wo0  = hw0 & 63;               // 0 or 32

    const int t    = threadIdx.x;
    const int wid  = t >> 6, lane = t & 63;
    const int arow = lane & 15;
    const int akk  = (lane >> 4) << 3;
    const int gp   = t >> 4;                 // gather position 0..31
    const int gq   = t & 15;                 // gather chunk (8 ch) 0..15
    const int swzp = (gp & 15) << 3;
    const ushort* xtb = xt + ((size_t)b << 19);   // b * 4096 * 128

    // ======== offset-conv prologue: stage 3 rows x 34 cols (zero-masked) ====
    // col q corresponds to image col wo0-1+q; OOB (row or col) -> zeros
#pragma unroll
    for (int it = 0; it < 4; ++it) {
        int i = t + it * 512;
        if (i < 3 * 34 * 16) {
            int rr  = i / 544;               // 544 = 34*16 (const div)
            int rem = i - rr * 544;
            int q   = rem >> 4;
            int ch  = rem & 15;
            int yr  = ho - 1 + rr;
            int sx  = wo0 - 1 + q;
            short8 val = {};
            if (yr >= 0 && yr < H_ && sx >= 0 && sx < W_)
                val = *reinterpret_cast<const short8*>(
                    xtb + (((size_t)((yr << 6) + sx)) << 7) + ch * 8);
            *reinterpret_cast<short8*>(
                &pro[rr][q][(ch * 8) ^ ((q & 7) << 3)]) = val;
        }
    }
    __syncthreads();

    // ================= offset-conv MFMA (B from LDS, no masking) ===========
    {
        const int wmO = (wid >> 1) & 1, wnO = wid & 1;  // M=32, N=32 (2x2),
        const int colq = wnO * 16 + arow;               // waves 4..7 duplicate
        f32x4 o0 = {}, o1 = {};
#pragma unroll
        for (int k = 0; k < K2_; ++k) {
            const int ky = k / 3, kx = k % 3;
            const int qr  = colq + kx;            // LDS row (0..33)
            const int key = (qr & 7) << 3;
            const ushort* ap = wt_off
                + (((size_t)(k * 32 + wmO * 16 + arow)) << 7) + akk;
#pragma unroll
            for (int kc = 0; kc < 4; ++kc) {
                short8 aO = *reinterpret_cast<const short8*>(ap + kc * 32);
                short8 bO = *reinterpret_cast<const short8*>(
                    &pro[ky][qr][(kc * 32 + akk) ^ key]);
                if (kc < 2) o0 = __builtin_amdgcn_mfma_f32_16x16x32_bf16(aO, bO, o0, 0, 0, 0);
                else        o1 = __builtin_amdgcn_mfma_f32_16x16x32_bf16(aO, bO, o1, 0, 0, 0);
            }
        }
        const int sO = wnO * 16 + arow;
#pragma unroll
        for (int r4 = 0; r4 < 4; ++r4) {
            int j = wmO * 16 + ((lane >> 4) << 2) + r4;
            if (j < JOFF_) s_off[j][sO] = o0[r4] + o1[r4] + b_off[j];
        }
    }
    __syncthreads();   // publishes s_off; retires pro (sB may now be written)

    // ================= fused gather + MFMA main loop =================
    f32x4  acc[2] = {};
    short8 aC[4];                            // single A buffer (reload trick)
    short8 gA[4], gB[4];                     // two static gather buffer sets
    float  cA[4], cB[4];                     // bilinear coefs per set

    auto load_a = [&](int k) {
        const ushort* wk = wt + (size_t)k * (COUT_ * C_)
                         + (wid * 16 + arow) * C_ + akk;
#pragma unroll
        for (int kc = 0; kc < 4; ++kc)
            aC[kc] = *reinterpret_cast<const short8*>(wk + kc * 32);
    };

    // issue 4 lane-adjacent 16B corner loads (8 ch: chunk gq)
    auto gather_load = [&](int k, short8 (&g)[4], float (&ca)[4]) {
        float dy = s_off[2*k    ][gp];
        float dx = s_off[2*k + 1][gp];
        float py = (float)(ho - 1 + k/3) + dy;
        float px = (float)(wo0 + gp - 1 + k%3) + dx;
        float y0f = floorf(py), x0f = floorf(px);
        float wy = py - y0f,    wx = px - x0f;
        int y0 = (int)y0f, x0 = (int)x0f;
        int y1 = y0 + 1,   x1 = x0 + 1;
        float vy0 = (y0 >= 0 && y0 < H_) ? 1.f : 0.f;
        float vy1 = (y1 >= 0 && y1 < H_) ? 1.f : 0.f;
        float vx0 = (x0 >= 0 && x0 < W_) ? 1.f : 0.f;
        float vx1 = (x1 >= 0 && x1 < W_) ? 1.f : 0.f;
        int y0c = min(max(y0, 0), H_-1), y1c = min(max(y1, 0), H_-1);
        int x0c = min(max(x0, 0), W_-1), x1c = min(max(x1, 0), W_-1);
        int bx  = min(max(x0, 0), W_-2);     // column pair [bx, bx+1]
        float wx0 = (1.f - wx) * vx0, wx1 = wx * vx1;
        float ex0 = (x0c == bx ? wx0 : 0.f) + (x1c == bx ? wx1 : 0.f);
        float ex1 = (x0c == bx ? 0.f : wx0) + (x1c == bx ? 0.f : wx1);
        float r0 = (1.f - wy) * vy0, r1 = wy * vy1;
        ca[0] = r0*ex0; ca[1] = r0*ex1; ca[2] = r1*ex0; ca[3] = r1*ex1;
        const ushort* r00 = xtb + (((y0c << 6) + bx) << 7) + gq * 8;
        const ushort* r10 = xtb + (((y1c << 6) + bx) << 7) + gq * 8;
        g[0] = *reinterpret_cast<const short8*>(r00);        // (y0,bx)
        g[1] = *reinterpret_cast<const short8*>(r00 + 128);  // (y0,bx+1)
        g[2] = *reinterpret_cast<const short8*>(r10);        // (y1,bx)
        g[3] = *reinterpret_cast<const short8*>(r10 + 128);  // (y1,bx+1)
    };

    // combine corners, pack (RNE via bfround+perm), one b128 store
    auto gather_math_store = [&](int buf, const short8 (&g)[4],
                                 const float (&ca)[4]) {
        float v[8];
#pragma unroll
        for (int q = 0; q < 8; ++q) {
            float vv = ca[0] * bf2f((ushort)g[0][q]);
            vv = fmaf(ca[1], bf2f((ushort)g[1][q]), vv);
            vv = fmaf(ca[2], bf2f((ushort)g[2][q]), vv);
            vv = fmaf(ca[3], bf2f((ushort)g[3][q]), vv);
            v[q] = vv;
        }
        uint4 pk;
        pk.x = bfpack(v[0], v[1]);
        pk.y = bfpack(v[2], v[3]);
        pk.z = bfpack(v[4], v[5]);
        pk.w = bfpack(v[6], v[7]);
        *reinterpret_cast<uint4*>(&sB[buf][gp][(gq * 8) ^ swzp]) = pk;
    };

    // ---- pipeline prologue: A(0)->aC; g(0)->gA; g(1)->gB; sB[0] from gA
    load_a(0);
    gather_load(0, gA, cA);
    gather_load(1, gB, cB);
    gather_math_store(0, gA, cA);
    asm volatile("s_waitcnt lgkmcnt(0)" ::: "memory");
    __builtin_amdgcn_s_barrier();

#pragma unroll
    for (int k = 0; k < K2_; ++k) {
        if (k + 2 < K2_) {                       // g(k+2) -> dead gather set
            if ((k & 1) == 0) gather_load(k + 2, gA, cA);
            else              gather_load(k + 2, gB, cB);
        }

        // ---- MFMA(k): LDS B, register A (aC loaded last iter)
        {
            const int buf = k & 1;
#pragma unroll
            for (int kc = 0; kc < 4; ++kc) {
#pragma unroll
                for (int ni = 0; ni < 2; ++ni) {
                    int srow = ni*16 + arow;
                    short8 bF = *reinterpret_cast<const short8*>(
                        &sB[buf][srow][(kc*32 + akk) ^ ((srow & 15) << 3)]);
                    acc[ni] = __builtin_amdgcn_mfma_f32_16x16x32_bf16(
                        aC[kc], bF, acc[ni], 0, 0, 0);
                }
            }
        }

        // keep the aC reload BELOW MFMA(k) so one buffer suffices
        __builtin_amdgcn_sched_barrier(0);

        if (k < K2_ - 1) {
            load_a(k + 1);                       // overwrites aC (now dead)
            if ((k & 1) == 0) gather_math_store((k + 1) & 1, gB, cB);
            else              gather_math_store((k + 1) & 1, gA, cA);
        }

        // RAW barrier: drain LDS ops only; VMEM prefetches stay in flight
        asm volatile("s_waitcnt lgkmcnt(0)" ::: "memory");
        __builtin_amdgcn_s_barrier();
    }

    // ---- epilogue: C/D layout col=lane&15, row=(lane>>4)*4+reg; nt stores
#pragma unroll
    for (int ni = 0; ni < 2; ++ni) {
#pragma unroll
        for (int r = 0; r < 4; ++r) {
            int o = wid*16 + ((lane >> 4) << 2) + r;
            int s = ni*16 + arow;
            __builtin_nontemporal_store(acc[ni][r],
                &out[(((size_t)(b*COUT_ + o)) << 12) + hw0 + s]);
        }
    }
}

// ---------------------------------------------------------------------------
extern "C" void kernel_launch(void* const* d_in, const int* in_sizes, int n_in,
                              void* d_out, int out_size, void* d_ws, size_t ws_size,
                              hipStream_t stream) {
    const float* x     = (const float*)d_in[0];
    const float* w_off = (const float*)d_in[1];
    const float* b_off = (const float*)d_in[2];
    const float* w_def = (const float*)d_in[3];
    float* out  = (float*)d_out;

    char* ws = (char*)d_ws;
    ushort* xtp    = (ushort*)ws;                         // 8,388,608 B
    ushort* wt     = (ushort*)(ws + 8388608);             //   294,912 B
    ushort* wt_off = (ushort*)(ws + 8388608 + 294912);    //    73,728 B

    // Kernel X: x -> NHWC bf16
    nhwc_kernel<<<1024, 512, 0, stream>>>(x, xtp);
    // Kernel T: both weight transposes
    {
        int total  = K2_ * COUT_ * C_ + K2_ * 32 * C_;    // 184,320
        transpose_w_kernel<<<(total + 255) / 256, 256, 0, stream>>>(
            w_def, w_off, wt, wt_off);
    }
    // Kernel B: fused offsets + gather + MFMA GEMM (1024 blocks, 32 pos each)
    deform_mfma_kernel<<<(B_ * HW_) / 32, 512, 0, stream>>>(
        xtp, wt, wt_off, b_off, out);
}

// Round 20
// 89.840 us; speedup vs baseline: 1.1564x; 1.1564x over previous
//
#include <hip/hip_runtime.h>
#include <hip/hip_bf16.h>

// Problem constants (from reference)
#define B_    8
#define C_    128
#define H_    64
#define W_    64
#define COUT_ 128
#define K2_   9
#define JOFF_ 18            // 2*K*K offset channels
#define HW_   (H_*W_)       // 4096
#define CK_   (C_*K2_)      // 1152

typedef short  short8 __attribute__((ext_vector_type(8)));   // 8 bf16 in 4 VGPR
typedef float  f32x4  __attribute__((ext_vector_type(4)));

__device__ __forceinline__ ushort f2bf(float f) {
    __hip_bfloat16 h = __float2bfloat16(f);
    return *reinterpret_cast<ushort*>(&h);
}
__device__ __forceinline__ float bf2f(ushort u) {
    return __uint_as_float(((uint)u) << 16);
}
// RNE-to-bf16 rounding kept in the HIGH 16 bits (bit-identical to
// __float2bfloat16 for non-NaN inputs): u + 0x7FFF + lsb(u>>16).
__device__ __forceinline__ uint bfround(float f) {
    uint u = __float_as_uint(f);
    return u + 0x7FFFu + ((u >> 16) & 1u);
}
// pack two rounded values: low16 = hi16(r0), high16 = hi16(r1) — one v_perm
__device__ __forceinline__ uint bfpack(float v0, float v1) {
    return __builtin_amdgcn_perm(bfround(v1), bfround(v0), 0x07060302u);
}

// ---------------------------------------------------------------------------
// Kernel P (fused prep): blocks 0..1023 = x NCHW f32 -> xt NHWC bf16;
// blocks 1024..1383 = both weight transposes (360 x 512 = 184320 elems).
// ---------------------------------------------------------------------------
__global__ __launch_bounds__(512) void prep_kernel(
    const float* __restrict__ x, const float* __restrict__ w_def,
    const float* __restrict__ w_off, ushort* __restrict__ xt,
    ushort* __restrict__ wt, ushort* __restrict__ wt_off)
{
    const int blk = blockIdx.x;
    const int t   = threadIdx.x;

    if (blk < 1024) {
        // ---- NHWC transpose: 8 b * 2 ct * 64 ht
        __shared__ float tile[64][65];
        const int ht = blk & 63;
        const int ct = (blk >> 6) & 1;
        const int b  = blk >> 7;
        const int tx = t & 63, ty = t >> 6;    // ty 0..7

        const float* xs = x + ((size_t)(b * C_ + ct * 64) << 12) + (ht << 6);
#pragma unroll
        for (int i = 0; i < 8; ++i) {
            int c = i * 8 + ty;
            tile[c][tx] = xs[((size_t)c << 12) + tx];
        }
        __syncthreads();

        const int r  = t >> 3;                 // position 0..63
        const int co = (t & 7) * 8;            // channel octet
        short8 pack;
#pragma unroll
        for (int j = 0; j < 8; ++j) pack[j] = (short)f2bf(tile[co + j][r]);
        *reinterpret_cast<short8*>(
            xt + ((((size_t)b << 12) + (ht << 6) + r) << 7) + ct * 64 + co) = pack;
    } else {
        // ---- weight transposes
        int i = (blk - 1024) * 512 + t;        // 0 .. 184319
        if (i < K2_ * COUT_ * C_) {
            int c = i & 127;
            int o = (i >> 7) & 127;
            int k = i >> 14;
            float v = w_def[((size_t)o * C_ + c) * K2_ + k];
            wt[((size_t)k * COUT_ + o) * C_ + c] = f2bf(v);
        } else {
            int j2 = i - K2_ * COUT_ * C_;     // < K2_*32*C_
            int c = j2 & 127;
            int j = (j2 >> 7) & 31;
            int k = j2 >> 12;
            float v = (j < JOFF_) ? w_off[((size_t)j * C_ + c) * K2_ + k] : 0.f;
            wt_off[(((size_t)k * 32) + j) * C_ + c] = f2bf(v);
        }
    }
}

// ---------------------------------------------------------------------------
// Kernel B: offset conv (LDS-staged MFMA prologue) + fused deformable
// gather + MFMA GEMM. r18 skeleton (tile 128x64, 512 blocks, 8 waves,
// (512,4), static depth-2 gather pipeline, bfpack). CHANGE: wave grid
// 2Mx4N -> 4Mx2N (wave = 32 outch x 32 pos): per-wave B ds_reads halve
// (16->8/tap, block LDS reads 128KB->64KB/tap); A single-buffered
// aC[2][4] reloaded post-MFMA under sched_barrier(0) (r12 trick), so
// net VGPR unchanged. acc[2][2]: same 4-deep MFMA chains as r18.
// ---------------------------------------------------------------------------
__global__ __launch_bounds__(512, 4) void deform_mfma_kernel(
    const ushort* __restrict__ xt, const ushort* __restrict__ wt,
    const ushort* __restrict__ wt_off, const float* __restrict__ b_off,
    float* __restrict__ out)
{
    __shared__ __align__(16) ushort smem[3 * 66 * C_];   // 50688 B union
    __shared__ float s_off[JOFF_][64];                   // 4.6 KB

    typedef ushort sB_t[2][64][C_];                      // 32768 B view
    typedef ushort pro_t[3][66][C_];                     // 50688 B view
    sB_t&  sB  = *reinterpret_cast<sB_t*>(smem);
    pro_t& pro = *reinterpret_cast<pro_t*>(smem);

    const int bid  = blockIdx.x;             // 512 blocks
    const int nbid = ((bid & 7) << 6) + (bid >> 3);   // XCD chunk: 1 image/XCD
    const int s0   = nbid << 6;
    const int b    = s0 >> 12;
    const int hw0  = s0 & (HW_ - 1);
    const int ho   = hw0 >> 6;

    const int t    = threadIdx.x;
    const int wid  = t >> 6, lane = t & 63;
    const int arow = lane & 15;
    const int akk  = (lane >> 4) << 3;
    const int gp   = t >> 3;                 // gather position 0..63
    const int gq   = t & 7;                  // gather chunk (8 ch) 0..7
    const int swzp = (gp & 15) << 3;
    const ushort* xtb = xt + ((size_t)b << 19);   // b * 4096 * 128

    // ================= offset-conv prologue: stage 3 rows =================
    if (t < 384) {
        int rr  = t >> 7, sub = t & 127;
        int q   = (sub & 64) ? 65 : 0;
        reinterpret_cast<uint*>(&pro[rr][q][0])[sub & 63] = 0u;
    }
#pragma unroll
    for (int it = 0; it < 6; ++it) {
        int i   = t + it * 512;
        int rr  = i >> 10;
        int rem = i & 1023;
        int pos = rem >> 4;
        int ch  = rem & 15;
        int yr  = ho - 1 + rr;
        short8 val = {};
        if (yr >= 0 && yr < H_)
            val = *reinterpret_cast<const short8*>(
                xtb + (((size_t)((yr << 6) + pos)) << 7) + ch * 8);
        int q = pos + 1;
        *reinterpret_cast<short8*>(
            &pro[rr][q][(ch * 8) ^ ((q & 7) << 3)]) = val;
    }
    __syncthreads();

    // ================= offset-conv MFMA (B from LDS, no masking) ===========
    {
        const int wmO = wid >> 2, wnO = wid & 3;  // M=32 (2x16), N=64 (4x16)
        const int colq = wnO * 16 + arow;         // output position s
        f32x4 o0 = {}, o1 = {};
#pragma unroll
        for (int k = 0; k < K2_; ++k) {
            const int ky = k / 3, kx = k % 3;
            const int qr  = colq + kx;            // LDS row = s + kx (0..65)
            const int key = (qr & 7) << 3;
            const ushort* ap = wt_off
                + (((size_t)(k * 32 + wmO * 16 + arow)) << 7) + akk;
#pragma unroll
            for (int kc = 0; kc < 4; ++kc) {
                short8 aO = *reinterpret_cast<const short8*>(ap + kc * 32);
                short8 bO = *reinterpret_cast<const short8*>(
                    &pro[ky][qr][(kc * 32 + akk) ^ key]);
                if (kc < 2) o0 = __builtin_amdgcn_mfma_f32_16x16x32_bf16(aO, bO, o0, 0, 0, 0);
                else        o1 = __builtin_amdgcn_mfma_f32_16x16x32_bf16(aO, bO, o1, 0, 0, 0);
            }
        }
        const int sO = wnO * 16 + arow;
#pragma unroll
        for (int r4 = 0; r4 < 4; ++r4) {
            int j = wmO * 16 + ((lane >> 4) << 2) + r4;
            if (j < JOFF_) s_off[j][sO] = o0[r4] + o1[r4] + b_off[j];
        }
    }
    __syncthreads();   // publishes s_off; retires pro (sB may now be written)

    // ================= fused gather + MFMA main loop =================
    const int wmD = wid >> 1;                // 0..3: out-ch tile (32 rows)
    const int wnD = wid & 1;                 // 0..1: position tile (32 cols)

    f32x4  acc[2][2] = {};
    short8 aC[2][4];                         // single A buffer (reload trick)
    short8 gA[4][2], gB[4][2];               // two static gather buffer sets
    float  cA[4], cB[4];                     // bilinear coefs per set

    auto load_a = [&](int k) {
        const ushort* wk = wt + (size_t)k * (COUT_ * C_) + akk;
#pragma unroll
        for (int mi = 0; mi < 2; ++mi)
#pragma unroll
            for (int kc = 0; kc < 4; ++kc)
                aC[mi][kc] = *reinterpret_cast<const short8*>(
                    wk + (wmD * 32 + mi * 16 + arow) * C_ + kc * 32);
    };

    // issue 8 lane-adjacent 16B corner loads (16 ch: chunks gq, gq+8)
    auto gather_load = [&](int k, short8 (&g)[4][2], float (&ca)[4]) {
        float dy = s_off[2*k    ][gp];
        float dx = s_off[2*k + 1][gp];
        float py = (float)(ho - 1 + k/3) + dy;
        float px = (float)(gp - 1 + k%3) + dx;
        float y0f = floorf(py), x0f = floorf(px);
        float wy = py - y0f,    wx = px - x0f;
        int y0 = (int)y0f, x0 = (int)x0f;
        int y1 = y0 + 1,   x1 = x0 + 1;
        float vy0 = (y0 >= 0 && y0 < H_) ? 1.f : 0.f;
        float vy1 = (y1 >= 0 && y1 < H_) ? 1.f : 0.f;
        float vx0 = (x0 >= 0 && x0 < W_) ? 1.f : 0.f;
        float vx1 = (x1 >= 0 && x1 < W_) ? 1.f : 0.f;
        int y0c = min(max(y0, 0), H_-1), y1c = min(max(y1, 0), H_-1);
        int x0c = min(max(x0, 0), W_-1), x1c = min(max(x1, 0), W_-1);
        int bx  = min(max(x0, 0), W_-2);     // column pair [bx, bx+1]
        float wx0 = (1.f - wx) * vx0, wx1 = wx * vx1;
        float ex0 = (x0c == bx ? wx0 : 0.f) + (x1c == bx ? wx1 : 0.f);
        float ex1 = (x0c == bx ? 0.f : wx0) + (x1c == bx ? 0.f : wx1);
        float r0 = (1.f - wy) * vy0, r1 = wy * vy1;
        ca[0] = r0*ex0; ca[1] = r0*ex1; ca[2] = r1*ex0; ca[3] = r1*ex1;
        const ushort* r00 = xtb + (((y0c << 6) + bx) << 7) + gq * 8;
        const ushort* r10 = xtb + (((y1c << 6) + bx) << 7) + gq * 8;
        g[0][0] = *reinterpret_cast<const short8*>(r00);        // (y0,bx)  lo
        g[0][1] = *reinterpret_cast<const short8*>(r00 + 64);   // (y0,bx)  hi
        g[1][0] = *reinterpret_cast<const short8*>(r00 + 128);  // (y0,bx+1)lo
        g[1][1] = *reinterpret_cast<const short8*>(r00 + 192);  // (y0,bx+1)hi
        g[2][0] = *reinterpret_cast<const short8*>(r10);        // (y1,bx)  lo
        g[2][1] = *reinterpret_cast<const short8*>(r10 + 64);   // (y1,bx)  hi
        g[3][0] = *reinterpret_cast<const short8*>(r10 + 128);  // (y1,bx+1)lo
        g[3][1] = *reinterpret_cast<const short8*>(r10 + 192);  // (y1,bx+1)hi
    };

    // combine corners, pack (RNE via bfround+perm), two b128 stores
    auto gather_math_store = [&](int buf, const short8 (&g)[4][2],
                                 const float (&ca)[4]) {
#pragma unroll
        for (int j = 0; j < 2; ++j) {
            float v[8];
#pragma unroll
            for (int q = 0; q < 8; ++q) {
                float vv = ca[0] * bf2f((ushort)g[0][j][q]);
                vv = fmaf(ca[1], bf2f((ushort)g[1][j][q]), vv);
                vv = fmaf(ca[2], bf2f((ushort)g[2][j][q]), vv);
                vv = fmaf(ca[3], bf2f((ushort)g[3][j][q]), vv);
                v[q] = vv;
            }
            uint4 pk;
            pk.x = bfpack(v[0], v[1]);
            pk.y = bfpack(v[2], v[3]);
            pk.z = bfpack(v[4], v[5]);
            pk.w = bfpack(v[6], v[7]);
            *reinterpret_cast<uint4*>(
                &sB[buf][gp][(gq * 8 + j * 64) ^ swzp]) = pk;
        }
    };

    // ---- pipeline prologue: A(0)->aC; g(0)->gA; g(1)->gB; sB[0] from gA
    load_a(0);
    gather_load(0, gA, cA);
    gather_load(1, gB, cB);
    gather_math_store(0, gA, cA);
    asm volatile("s_waitcnt lgkmcnt(0)" ::: "memory");
    __builtin_amdgcn_s_barrier();

#pragma unroll
    for (int k = 0; k < K2_; ++k) {
        if (k + 2 < K2_) {                       // g(k+2) -> dead gather set
            if ((k & 1) == 0) gather_load(k + 2, gA, cA);
            else              gather_load(k + 2, gB, cB);
        }

        // ---- MFMA(k): 8 B ds_reads (2 ni x 4 kc), 16 MFMA, A in aC regs
        {
            const int buf = k & 1;
#pragma unroll
            for (int kc = 0; kc < 4; ++kc) {
#pragma unroll
                for (int ni = 0; ni < 2; ++ni) {
                    int srow = wnD * 32 + ni * 16 + arow;
                    short8 bF = *reinterpret_cast<const short8*>(
                        &sB[buf][srow][(kc*32 + akk) ^ ((srow & 15) << 3)]);
#pragma unroll
                    for (int mi = 0; mi < 2; ++mi)
                        acc[mi][ni] = __builtin_amdgcn_mfma_f32_16x16x32_bf16(
                            aC[mi][kc], bF, acc[mi][ni], 0, 0, 0);
                }
            }
        }

        // keep the aC reload BELOW MFMA(k) so one buffer suffices
        __builtin_amdgcn_sched_barrier(0);

        if (k < K2_ - 1) {
            load_a(k + 1);                       // overwrites aC (now dead)
            if ((k & 1) == 0) gather_math_store((k + 1) & 1, gB, cB);
            else              gather_math_store((k + 1) & 1, gA, cA);
        }

        // RAW barrier: drain LDS ops only; VMEM prefetches stay in flight
        asm volatile("s_waitcnt lgkmcnt(0)" ::: "memory");
        __builtin_amdgcn_s_barrier();
    }

    // ---- epilogue: C/D layout col=lane&15, row=(lane>>4)*4+reg; nt stores
#pragma unroll
    for (int mi = 0; mi < 2; ++mi) {
#pragma unroll
        for (int ni = 0; ni < 2; ++ni) {
#pragma unroll
            for (int r = 0; r < 4; ++r) {
                int o = wmD*32 + mi*16 + ((lane >> 4) << 2) + r;
                int s = wnD*32 + ni*16 + arow;
                __builtin_nontemporal_store(acc[mi][ni][r],
                    &out[(((size_t)(b*COUT_ + o)) << 12) + hw0 + s]);
            }
        }
    }
}

// ---------------------------------------------------------------------------
extern "C" void kernel_launch(void* const* d_in, const int* in_sizes, int n_in,
                              void* d_out, int out_size, void* d_ws, size_t ws_size,
                              hipStream_t stream) {
    const float* x     = (const float*)d_in[0];
    const float* w_off = (const float*)d_in[1];
    const float* b_off = (const float*)d_in[2];
    const float* w_def = (const float*)d_in[3];
    float* out  = (float*)d_out;

    char* ws = (char*)d_ws;
    ushort* xtp    = (ushort*)ws;                         // 8,388,608 B
    ushort* wt     = (ushort*)(ws + 8388608);             //   294,912 B
    ushort* wt_off = (ushort*)(ws + 8388608 + 294912);    //    73,728 B

    // Kernel P: fused prep (NHWC transpose + both weight transposes)
    prep_kernel<<<1384, 512, 0, stream>>>(x, w_def, w_off, xtp, wt, wt_off);
    // Kernel B: fused offsets + gather + MFMA GEMM (512 blocks, 64 pos each)
    deform_mfma_kernel<<<(B_ * HW_) / 64, 512, 0, stream>>>(
        xtp, wt, wt_off, b_off, out);
}

// Round 21
// 57.317 us; speedup vs baseline: 1.8126x; 1.5674x over previous
//
#include <hip/hip_runtime.h>
#include <hip/hip_bf16.h>

// Problem constants (from reference)
#define B_    8
#define C_    128
#define H_    64
#define W_    64
#define COUT_ 128
#define K2_   9
#define JOFF_ 18            // 2*K*K offset channels
#define HW_   (H_*W_)       // 4096
#define CK_   (C_*K2_)      // 1152

typedef short  short8 __attribute__((ext_vector_type(8)));   // 8 bf16 in 4 VGPR
typedef float  f32x4  __attribute__((ext_vector_type(4)));

__device__ __forceinline__ ushort f2bf(float f) {
    __hip_bfloat16 h = __float2bfloat16(f);
    return *reinterpret_cast<ushort*>(&h);
}
__device__ __forceinline__ float bf2f(ushort u) {
    return __uint_as_float(((uint)u) << 16);
}
// RNE-to-bf16 rounding kept in the HIGH 16 bits (bit-identical to
// __float2bfloat16 for non-NaN inputs): u + 0x7FFF + lsb(u>>16).
__device__ __forceinline__ uint bfround(float f) {
    uint u = __float_as_uint(f);
    return u + 0x7FFFu + ((u >> 16) & 1u);
}
// pack two rounded values: low16 = hi16(r0), high16 = hi16(r1) — one v_perm
__device__ __forceinline__ uint bfpack(float v0, float v1) {
    return __builtin_amdgcn_perm(bfround(v1), bfround(v0), 0x07060302u);
}

// ---------------------------------------------------------------------------
// Kernel P (fused prep): blocks 0..1023 = x NCHW f32 -> xt NHWC bf16;
// blocks 1024..1383 = both weight transposes (360 x 512 = 184320 elems).
// ---------------------------------------------------------------------------
__global__ __launch_bounds__(512) void prep_kernel(
    const float* __restrict__ x, const float* __restrict__ w_def,
    const float* __restrict__ w_off, ushort* __restrict__ xt,
    ushort* __restrict__ wt, ushort* __restrict__ wt_off)
{
    const int blk = blockIdx.x;
    const int t   = threadIdx.x;

    if (blk < 1024) {
        // ---- NHWC transpose: 8 b * 2 ct * 64 ht
        __shared__ float tile[64][65];
        const int ht = blk & 63;
        const int ct = (blk >> 6) & 1;
        const int b  = blk >> 7;
        const int tx = t & 63, ty = t >> 6;    // ty 0..7

        const float* xs = x + ((size_t)(b * C_ + ct * 64) << 12) + (ht << 6);
#pragma unroll
        for (int i = 0; i < 8; ++i) {
            int c = i * 8 + ty;
            tile[c][tx] = xs[((size_t)c << 12) + tx];
        }
        __syncthreads();

        const int r  = t >> 3;                 // position 0..63
        const int co = (t & 7) * 8;            // channel octet
        short8 pack;
#pragma unroll
        for (int j = 0; j < 8; ++j) pack[j] = (short)f2bf(tile[co + j][r]);
        *reinterpret_cast<short8*>(
            xt + ((((size_t)b << 12) + (ht << 6) + r) << 7) + ct * 64 + co) = pack;
    } else {
        // ---- weight transposes
        int i = (blk - 1024) * 512 + t;        // 0 .. 184319
        if (i < K2_ * COUT_ * C_) {
            int c = i & 127;
            int o = (i >> 7) & 127;
            int k = i >> 14;
            float v = w_def[((size_t)o * C_ + c) * K2_ + k];
            wt[((size_t)k * COUT_ + o) * C_ + c] = f2bf(v);
        } else {
            int j2 = i - K2_ * COUT_ * C_;     // < K2_*32*C_
            int c = j2 & 127;
            int j = (j2 >> 7) & 31;
            int k = j2 >> 12;
            float v = (j < JOFF_) ? w_off[((size_t)j * C_ + c) * K2_ + k] : 0.f;
            wt_off[(((size_t)k * 32) + j) * C_ + c] = f2bf(v);
        }
    }
}

// ---------------------------------------------------------------------------
// Kernel B: offset conv (LDS-staged MFMA prologue) + fused deformable
// gather + MFMA GEMM — r18's proven 51.2us configuration, byte-identical.
// Tile 128 outch x 64 pos, 512 blocks, 8 waves (2Mx4N), (512,4), static
// depth-2 gather pipeline (gA/gB), static A parity (aA/aB), bfpack.
// r20's 4Mx2N wave grid REVERTED (spilled: WRITE 18->101MB).
// ---------------------------------------------------------------------------
__global__ __launch_bounds__(512, 4) void deform_mfma_kernel(
    const ushort* __restrict__ xt, const ushort* __restrict__ wt,
    const ushort* __restrict__ wt_off, const float* __restrict__ b_off,
    float* __restrict__ out)
{
    __shared__ __align__(16) ushort smem[3 * 66 * C_];   // 50688 B union
    __shared__ float s_off[JOFF_][64];                   // 4.6 KB

    typedef ushort sB_t[2][64][C_];                      // 32768 B view
    typedef ushort pro_t[3][66][C_];                     // 50688 B view
    sB_t&  sB  = *reinterpret_cast<sB_t*>(smem);
    pro_t& pro = *reinterpret_cast<pro_t*>(smem);

    const int bid  = blockIdx.x;             // 512 blocks
    const int nbid = ((bid & 7) << 6) + (bid >> 3);   // XCD chunk: 1 image/XCD
    const int s0   = nbid << 6;
    const int b    = s0 >> 12;
    const int hw0  = s0 & (HW_ - 1);
    const int ho   = hw0 >> 6;

    const int t    = threadIdx.x;
    const int wid  = t >> 6, lane = t & 63;
    const int arow = lane & 15;
    const int akk  = (lane >> 4) << 3;
    const int gp   = t >> 3;                 // gather position 0..63
    const int gq   = t & 7;                  // gather chunk (8 ch) 0..7
    const int swzp = (gp & 15) << 3;
    const ushort* xtb = xt + ((size_t)b << 19);   // b * 4096 * 128

    // ================= offset-conv prologue: stage 3 rows =================
    if (t < 384) {
        int rr  = t >> 7, sub = t & 127;
        int q   = (sub & 64) ? 65 : 0;
        reinterpret_cast<uint*>(&pro[rr][q][0])[sub & 63] = 0u;
    }
#pragma unroll
    for (int it = 0; it < 6; ++it) {
        int i   = t + it * 512;
        int rr  = i >> 10;
        int rem = i & 1023;
        int pos = rem >> 4;
        int ch  = rem & 15;
        int yr  = ho - 1 + rr;
        short8 val = {};
        if (yr >= 0 && yr < H_)
            val = *reinterpret_cast<const short8*>(
                xtb + (((size_t)((yr << 6) + pos)) << 7) + ch * 8);
        int q = pos + 1;
        *reinterpret_cast<short8*>(
            &pro[rr][q][(ch * 8) ^ ((q & 7) << 3)]) = val;
    }
    __syncthreads();

    // ================= offset-conv MFMA (B from LDS, no masking) ===========
    {
        const int wmO = wid >> 2, wnO = wid & 3;  // M=32 (2x16), N=64 (4x16)
        const int colq = wnO * 16 + arow;         // output position s
        f32x4 o0 = {}, o1 = {};
#pragma unroll
        for (int k = 0; k < K2_; ++k) {
            const int ky = k / 3, kx = k % 3;
            const int qr  = colq + kx;            // LDS row = s + kx (0..65)
            const int key = (qr & 7) << 3;
            const ushort* ap = wt_off
                + (((size_t)(k * 32 + wmO * 16 + arow)) << 7) + akk;
#pragma unroll
            for (int kc = 0; kc < 4; ++kc) {
                short8 aO = *reinterpret_cast<const short8*>(ap + kc * 32);
                short8 bO = *reinterpret_cast<const short8*>(
                    &pro[ky][qr][(kc * 32 + akk) ^ key]);
                if (kc < 2) o0 = __builtin_amdgcn_mfma_f32_16x16x32_bf16(aO, bO, o0, 0, 0, 0);
                else        o1 = __builtin_amdgcn_mfma_f32_16x16x32_bf16(aO, bO, o1, 0, 0, 0);
            }
        }
        const int sO = wnO * 16 + arow;
#pragma unroll
        for (int r4 = 0; r4 < 4; ++r4) {
            int j = wmO * 16 + ((lane >> 4) << 2) + r4;
            if (j < JOFF_) s_off[j][sO] = o0[r4] + o1[r4] + b_off[j];
        }
    }
    __syncthreads();   // publishes s_off; retires pro (sB may now be written)

    // ================= fused gather + MFMA main loop =================
    f32x4  acc[4] = {};
    short8 aA[4], aB[4];                     // static A parity buffers
    short8 gA[4][2], gB[4][2];               // two static gather buffer sets
    float  cA[4], cB[4];                     // bilinear coefs per set

    auto load_a = [&](int k, short8 (&dst)[4]) {
        const ushort* wk = wt + (size_t)k * (COUT_ * C_)
                         + (wid * 16 + arow) * C_ + akk;
#pragma unroll
        for (int kc = 0; kc < 4; ++kc)
            dst[kc] = *reinterpret_cast<const short8*>(wk + kc * 32);
    };

    // issue 8 lane-adjacent 16B corner loads (16 ch: chunks gq, gq+8)
    auto gather_load = [&](int k, short8 (&g)[4][2], float (&ca)[4]) {
        float dy = s_off[2*k    ][gp];
        float dx = s_off[2*k + 1][gp];
        float py = (float)(ho - 1 + k/3) + dy;
        float px = (float)(gp - 1 + k%3) + dx;
        float y0f = floorf(py), x0f = floorf(px);
        float wy = py - y0f,    wx = px - x0f;
        int y0 = (int)y0f, x0 = (int)x0f;
        int y1 = y0 + 1,   x1 = x0 + 1;
        float vy0 = (y0 >= 0 && y0 < H_) ? 1.f : 0.f;
        float vy1 = (y1 >= 0 && y1 < H_) ? 1.f : 0.f;
        float vx0 = (x0 >= 0 && x0 < W_) ? 1.f : 0.f;
        float vx1 = (x1 >= 0 && x1 < W_) ? 1.f : 0.f;
        int y0c = min(max(y0, 0), H_-1), y1c = min(max(y1, 0), H_-1);
        int x0c = min(max(x0, 0), W_-1), x1c = min(max(x1, 0), W_-1);
        int bx  = min(max(x0, 0), W_-2);     // column pair [bx, bx+1]
        float wx0 = (1.f - wx) * vx0, wx1 = wx * vx1;
        float ex0 = (x0c == bx ? wx0 : 0.f) + (x1c == bx ? wx1 : 0.f);
        float ex1 = (x0c == bx ? 0.f : wx0) + (x1c == bx ? 0.f : wx1);
        float r0 = (1.f - wy) * vy0, r1 = wy * vy1;
        ca[0] = r0*ex0; ca[1] = r0*ex1; ca[2] = r1*ex0; ca[3] = r1*ex1;
        const ushort* r00 = xtb + (((y0c << 6) + bx) << 7) + gq * 8;
        const ushort* r10 = xtb + (((y1c << 6) + bx) << 7) + gq * 8;
        g[0][0] = *reinterpret_cast<const short8*>(r00);        // (y0,bx)  lo
        g[0][1] = *reinterpret_cast<const short8*>(r00 + 64);   // (y0,bx)  hi
        g[1][0] = *reinterpret_cast<const short8*>(r00 + 128);  // (y0,bx+1)lo
        g[1][1] = *reinterpret_cast<const short8*>(r00 + 192);  // (y0,bx+1)hi
        g[2][0] = *reinterpret_cast<const short8*>(r10);        // (y1,bx)  lo
        g[2][1] = *reinterpret_cast<const short8*>(r10 + 64);   // (y1,bx)  hi
        g[3][0] = *reinterpret_cast<const short8*>(r10 + 128);  // (y1,bx+1)lo
        g[3][1] = *reinterpret_cast<const short8*>(r10 + 192);  // (y1,bx+1)hi
    };

    // combine corners, pack (RNE via bfround+perm), two b128 stores
    auto gather_math_store = [&](int buf, const short8 (&g)[4][2],
                                 const float (&ca)[4]) {
#pragma unroll
        for (int j = 0; j < 2; ++j) {
            float v[8];
#pragma unroll
            for (int q = 0; q < 8; ++q) {
                float vv = ca[0] * bf2f((ushort)g[0][j][q]);
                vv = fmaf(ca[1], bf2f((ushort)g[1][j][q]), vv);
                vv = fmaf(ca[2], bf2f((ushort)g[2][j][q]), vv);
                vv = fmaf(ca[3], bf2f((ushort)g[3][j][q]), vv);
                v[q] = vv;
            }
            uint4 pk;
            pk.x = bfpack(v[0], v[1]);
            pk.y = bfpack(v[2], v[3]);
            pk.z = bfpack(v[4], v[5]);
            pk.w = bfpack(v[6], v[7]);
            *reinterpret_cast<uint4*>(
                &sB[buf][gp][(gq * 8 + j * 64) ^ swzp]) = pk;
        }
    };

    // ---- pipeline prologue: A(0)->aA; g(0)->gA; g(1)->gB; sB[0] from gA
    load_a(0, aA);
    gather_load(0, gA, cA);
    gather_load(1, gB, cB);
    gather_math_store(0, gA, cA);
    asm volatile("s_waitcnt lgkmcnt(0)" ::: "memory");
    __builtin_amdgcn_s_barrier();

#pragma unroll
    for (int k = 0; k < K2_; ++k) {
        // A(k+1) into the opposite parity buffer (compile-time selection)
        if (k < K2_ - 1) {
            if ((k & 1) == 0) load_a(k + 1, aB);
            else              load_a(k + 1, aA);
        }
        if (k + 2 < K2_) {                       // g(k+2) -> dead gather set
            if ((k & 1) == 0) gather_load(k + 2, gA, cA);
            else              gather_load(k + 2, gB, cB);
        }

        // ---- MFMA(k): LDS B, register A (parity buffer, drained long ago)
        {
            const short8 (&a)[4] = ((k & 1) == 0) ? aA : aB;
            const int buf = k & 1;
#pragma unroll
            for (int kc = 0; kc < 4; ++kc) {
#pragma unroll
                for (int ni = 0; ni < 4; ++ni) {
                    int srow = ni*16 + arow;
                    short8 bF = *reinterpret_cast<const short8*>(
                        &sB[buf][srow][(kc*32 + akk) ^ ((srow & 15) << 3)]);
                    acc[ni] = __builtin_amdgcn_mfma_f32_16x16x32_bf16(
                        a[kc], bF, acc[ni], 0, 0, 0);
                }
            }
        }

        if (k < K2_ - 1) {                       // math(k+1) from other set
            if ((k & 1) == 0) gather_math_store((k + 1) & 1, gB, cB);
            else              gather_math_store((k + 1) & 1, gA, cA);
        }

        // RAW barrier: drain LDS ops only; VMEM prefetches stay in flight
        asm volatile("s_waitcnt lgkmcnt(0)" ::: "memory");
        __builtin_amdgcn_s_barrier();
    }

    // ---- epilogue: C/D layout col=lane&15, row=(lane>>4)*4+reg; nt stores
#pragma unroll
    for (int ni = 0; ni < 4; ++ni) {
#pragma unroll
        for (int r = 0; r < 4; ++r) {
            int o = wid*16 + ((lane >> 4) << 2) + r;
            int s = ni*16 + arow;
            __builtin_nontemporal_store(acc[ni][r],
                &out[(((size_t)(b*COUT_ + o)) << 12) + hw0 + s]);
        }
    }
}

// ---------------------------------------------------------------------------
extern "C" void kernel_launch(void* const* d_in, const int* in_sizes, int n_in,
                              void* d_out, int out_size, void* d_ws, size_t ws_size,
                              hipStream_t stream) {
    const float* x     = (const float*)d_in[0];
    const float* w_off = (const float*)d_in[1];
    const float* b_off = (const float*)d_in[2];
    const float* w_def = (const float*)d_in[3];
    float* out  = (float*)d_out;

    char* ws = (char*)d_ws;
    ushort* xtp    = (ushort*)ws;                         // 8,388,608 B
    ushort* wt     = (ushort*)(ws + 8388608);             //   294,912 B
    ushort* wt_off = (ushort*)(ws + 8388608 + 294912);    //    73,728 B

    // Kernel P: fused prep (NHWC transpose + both weight transposes)
    prep_kernel<<<1384, 512, 0, stream>>>(x, w_def, w_off, xtp, wt, wt_off);
    // Kernel B: fused offsets + gather + MFMA GEMM (512 blocks, 64 pos each)
    deform_mfma_kernel<<<(B_ * HW_) / 64, 512, 0, stream>>>(
        xtp, wt, wt_off, b_off, out);
}